// Round 16
// baseline (453.196 us; speedup 1.0000x reference)
//
#include <hip/hip_runtime.h>
#include <hip/hip_bf16.h>
#include <stdint.h>

// Attention_48241072668890: x@Wq^T -> flash-attn over fp32 KV cache -> @Wo^T
// R16: delete both pure-conversion dispatches (prep_a, conv_wo ~40-45us of
// serial critical path). The fused gemm phase stages x and wq DIRECTLY as
// f32 (global_load_lds moves bytes), converting to bf16 during the frag
// read (2x ds_read_b128 f32x4 + f2bf). gemmO stages wo f32 likewise.
// f32 tiles use the verified source-XOR swizzle (chunk^(row&7) on the
// global addr, linear LDS dest, same XOR on read) => 2-way banks = free;
// naive layout would be 16-way. attn Phase B byte-identical to R15.
// Kernels: prep_b -> fused_qattn -> gemm_o.  (3 dispatches)

#define DIM   4096
#define NH    32
#define HD    128
#define BB    2
#define SS    1024
#define CC    2048

typedef __bf16 bf16x8 __attribute__((ext_vector_type(8)));
typedef float  f32x4  __attribute__((ext_vector_type(4)));

__device__ __forceinline__ unsigned short f2bf(float f) {
  union { __hip_bfloat16 h; unsigned short u; } cv;
  cv.h = __float2bfloat16(f);
  return cv.u;
}

__device__ __forceinline__ void gl_lds16(const void* g, void* l) {
  __builtin_amdgcn_global_load_lds(
      (__attribute__((address_space(1))) void*)(uintptr_t)(g),
      (__attribute__((address_space(3))) void*)(l), 16, 0, 0);
}

// build bf16x8 frag from two swizzled f32x4 LDS chunks
__device__ __forceinline__ bf16x8 frag_from_f32(const char* base, int row, int g) {
  const int s = row & 7;
  f32x4 c0 = *(const f32x4*)(base + row * 128 + (((2 * g)    ) ^ s) * 16);
  f32x4 c1 = *(const f32x4*)(base + row * 128 + (((2 * g) | 1) ^ s) * 16);
  union { bf16x8 v; unsigned short u[8]; } r;
  r.u[0] = f2bf(c0[0]); r.u[1] = f2bf(c0[1]); r.u[2] = f2bf(c0[2]); r.u[3] = f2bf(c0[3]);
  r.u[4] = f2bf(c1[0]); r.u[5] = f2bf(c1[1]); r.u[6] = f2bf(c1[2]); r.u[7] = f2bf(c1[3]);
  return r.v;
}

// ------- prep_b: k-conv | v^T (vectorized write) | mask flags --------------
__global__ __launch_bounds__(256) void prep_b(
    const float* __restrict__ ck,  unsigned short* __restrict__ kbf,
    const float* __restrict__ cv,  unsigned short* __restrict__ vtbf,
    const float* __restrict__ mask, int* __restrict__ flags)
{
  const int b = blockIdx.x, t = threadIdx.x;

  if (b < 2048) {                 // cache_k [B,C,NH,HD] -> [B*NH,C,HD] bf16
    const int total4 = BB * NH * CC * HD / 4;
    for (int i = b * 256 + t; i < total4; i += 2048 * 256) {
      size_t o = (size_t)i * 4;
      int d  = (int)(o & (HD - 1));
      size_t r = o >> 7;
      int c  = (int)(r & (CC - 1));
      int bh = (int)(r >> 11);
      int hh = bh & (NH - 1), bb = bh >> 5;
      float4 v = *reinterpret_cast<const float4*>(ck + ((size_t)(bb * CC + c) * NH + hh) * HD + d);
      ushort4 u; u.x = f2bf(v.x); u.y = f2bf(v.y); u.z = f2bf(v.z); u.w = f2bf(v.w);
      *reinterpret_cast<ushort4*>(kbf + o) = u;
    }
  } else if (b < 6144) {          // cache_v [B,C,NH,HD] -> [B*NH,HD,C] bf16
    __shared__ float tile[64][65];
    const int e  = b - 2048;
    const int ct = e & 31, rest = e >> 5;
    const int dt = rest & 1, bh = rest >> 1;
    const int hh = bh & (NH - 1), bb = bh >> 5;
    const int c0 = ct * 64, d0 = dt * 64;
    const int tx = t & 63, ty = t >> 6;           // 64 x 4
#pragma unroll
    for (int i = 0; i < 16; ++i) {
      int cl = ty + i * 4;
      tile[cl][tx] = cv[((size_t)(bb * CC + c0 + cl) * NH + hh) * HD + d0 + tx];
    }
    __syncthreads();
    const int c4 = (t & 15) * 4, dr = t >> 4;
#pragma unroll
    for (int i = 0; i < 4; ++i) {
      int dl = dr + i * 16;
      ushort4 o;
      o.x = f2bf(tile[c4 + 0][dl]); o.y = f2bf(tile[c4 + 1][dl]);
      o.z = f2bf(tile[c4 + 2][dl]); o.w = f2bf(tile[c4 + 3][dl]);
      *reinterpret_cast<ushort4*>(&vtbf[((size_t)bh * HD + d0 + dl) * CC + c0 + c4]) = o;
    }
  } else {                        // mask flags: flag[qt*32+ct] = any != 0
    __shared__ int s[4];
    const int e  = b - 6144;
    const int qt = e >> 5, ct = e & 31;
    const int w = t >> 6;
    const float4* m4 = (const float4*)mask;
    int nz = 0;
#pragma unroll
    for (int i = 0; i < 8; ++i) {
      int idx = i * 256 + t;
      int row = idx >> 4, c4 = idx & 15;
      float4 v = m4[(size_t)(qt * 128 + row) * (CC / 4) + ct * 16 + c4];
      nz |= (v.x != 0.f) | (v.y != 0.f) | (v.z != 0.f) | (v.w != 0.f);
    }
    int wa = (int)__any(nz);
    if ((t & 63) == 0) s[w] = wa;
    __syncthreads();
    if (t == 0) flags[qt * 32 + ct] = s[0] | s[1] | s[2] | s[3];
  }
}

// ---------------- gemmO: out[M,N] = attn[M,K](bf16) * wo[N,K](f32)^T ------
// A staged bf16 (m97 pattern); B staged f32 with source-XOR swizzle + cvt
// on frag read. M=2048 N=4096 K=4096, identity tile map, f32 output.
__global__ __launch_bounds__(256) void gemm_o(
    const unsigned short* __restrict__ A,
    const float* __restrict__ Bw,
    float* __restrict__ Cout)
{
  __shared__ __align__(16) unsigned short As[128 * 32];   // 8 KB
  __shared__ __align__(16) float Bsf[128 * 32];           // 16 KB
  const int t = threadIdx.x;
  const int w = t >> 6, lane = t & 63;
  const int l15 = lane & 15, g = lane >> 4;
  const int wr = w >> 1, wc = w & 1;
  const int bm0 = blockIdx.y * 128, bn0 = blockIdx.x * 128;

  const unsigned short* aSrc = A + (size_t)(bm0 + (t >> 2)) * DIM + (t & 3) * 8;
  // B f32: row = i*32 + (t>>3), chunk(16B = 4 f32) = (t&7) ^ (row&7)
  const float* bSrc = Bw + (size_t)(bn0 + (t >> 3)) * DIM + ((t & 7) ^ ((t >> 3) & 7)) * 4;
  char* aDst = (char*)As + w * 1024;
  char* bDst = (char*)Bsf + w * 1024;
  const size_t halfA = (size_t)64 * DIM;

  f32x4 acc[4][4];
#pragma unroll
  for (int m = 0; m < 4; ++m)
#pragma unroll
    for (int n = 0; n < 4; ++n) acc[m][n] = (f32x4){0.f, 0.f, 0.f, 0.f};

  for (int k0 = 0; k0 < DIM; k0 += 32) {
    gl_lds16(aSrc,         aDst);
    gl_lds16(aSrc + halfA, aDst + 4096);
#pragma unroll
    for (int i = 0; i < 4; ++i)
      gl_lds16(bSrc + (size_t)(i * 32) * DIM, bDst + i * 4096);
    aSrc += 32; bSrc += 32;
    __syncthreads();

    bf16x8 af[4], bf[4];
#pragma unroll
    for (int m = 0; m < 4; ++m)
      af[m] = *(const bf16x8*)&As[(wr * 64 + m * 16 + l15) * 32 + g * 8];
#pragma unroll
    for (int n = 0; n < 4; ++n)
      bf[n] = frag_from_f32((const char*)Bsf, wc * 64 + n * 16 + l15, g);
#pragma unroll
    for (int m = 0; m < 4; ++m)
#pragma unroll
      for (int n = 0; n < 4; ++n)
        acc[m][n] = __builtin_amdgcn_mfma_f32_16x16x32_bf16(af[m], bf[n], acc[m][n], 0, 0, 0);
    __syncthreads();
  }

  const int r0 = g * 4;
#pragma unroll
  for (int m = 0; m < 4; ++m) {
#pragma unroll
    for (int n = 0; n < 4; ++n) {
      int row = bm0 + wr * 64 + m * 16 + r0;
      int col = bn0 + wc * 64 + n * 16 + l15;
#pragma unroll
      for (int r = 0; r < 4; ++r)
        Cout[(size_t)(row + r) * DIM + col] = acc[m][n][r];
    }
  }
}

// ------------- fused gemmQ + flash attention (f32 direct staging) ---------
// Phase A: Q tile = x[f32] @ wq[f32]^T via bf16 MFMA — both operands staged
//   f32 (A = SM bytes [0,16K), B = [16K,32K)), source-XOR swizzled, cvt on
//   frag read. Phase H: C-frags -> Qh LDS (bytes [0,32K), swizzled, scale
//   folded) -> qf regs. Phase B: R9/R15-verbatim attn loop.
__global__ __launch_bounds__(256, 2) void fused_qattn(
    const float* __restrict__ Xf,              // x f32 [B*S, DIM]
    const float* __restrict__ Wqf,             // wq f32 [DIM, DIM]
    const unsigned short* __restrict__ Kb,
    const unsigned short* __restrict__ Vtb,
    const float* __restrict__ mask,
    const int* __restrict__ Mf,
    unsigned short* __restrict__ Ob)           // qbf (attn out)
{
  __shared__ __align__(16) unsigned short SM[40960];   // 80 KB

  const int t = threadIdx.x, w = t >> 6, lane = t & 63;
  const int lg = (blockIdx.x & 7) * 64 + (blockIdx.x >> 3);  // XCD-chunked remap
  const int qt = lg & 7, bh = lg >> 3;
  const int hh = bh & (NH - 1), bb = bh >> 5;
  const int q0 = qt * 128;
  const int l15 = lane & 15, g = lane >> 4;
  const int rb4 = g * 4;
  const int wr = w >> 1, wc = w & 1;

  // ---------------- Phase A: gemm with f32-staged operands
  const int bm0 = bb * SS + q0;       // global A row (x)
  const int bn0 = hh * HD;            // global B row (wq)
  {
    // f32 tile staging map: row = i*32 + (t>>3); chunk = (t&7) ^ (row&7)
    const float* aS = Xf  + (size_t)(bm0 + (t >> 3)) * DIM + ((t & 7) ^ ((t >> 3) & 7)) * 4;
    const float* bS = Wqf + (size_t)(bn0 + (t >> 3)) * DIM + ((t & 7) ^ ((t >> 3) & 7)) * 4;
    char* aDst = (char*)SM + w * 1024;           // bytes [0,16K)
    char* bDst = (char*)SM + 16384 + w * 1024;   // bytes [16K,32K)

    f32x4 acc[4][4];
#pragma unroll
    for (int m = 0; m < 4; ++m)
#pragma unroll
      for (int n = 0; n < 4; ++n) acc[m][n] = (f32x4){0.f, 0.f, 0.f, 0.f};

    for (int k0 = 0; k0 < DIM; k0 += 32) {
#pragma unroll
      for (int i = 0; i < 4; ++i) {
        gl_lds16(aS + (size_t)(i * 32) * DIM, aDst + i * 4096);
        gl_lds16(bS + (size_t)(i * 32) * DIM, bDst + i * 4096);
      }
      aS += 32; bS += 32;
      __syncthreads();

      bf16x8 af[4], bf[4];
#pragma unroll
      for (int m = 0; m < 4; ++m)
        af[m] = frag_from_f32((const char*)SM, wr * 64 + m * 16 + l15, g);
#pragma unroll
      for (int n = 0; n < 4; ++n)
        bf[n] = frag_from_f32((const char*)SM + 16384, wc * 64 + n * 16 + l15, g);
#pragma unroll
      for (int m = 0; m < 4; ++m)
#pragma unroll
        for (int n = 0; n < 4; ++n)
          acc[m][n] = __builtin_amdgcn_mfma_f32_16x16x32_bf16(af[m], bf[n], acc[m][n], 0, 0, 0);
      __syncthreads();
    }

    // ---------------- Phase H: C-frags -> Qh (swizzled) -> qf registers
    const float qscale = 0.12751744682f;     // (1/sqrt(128)) * log2(e)
    const int r0 = g * 4;
#pragma unroll
    for (int m = 0; m < 4; ++m) {
#pragma unroll
      for (int n = 0; n < 4; ++n) {
        int rl = wr * 64 + m * 16 + r0;
        int cl2 = wc * 64 + n * 16 + l15;
#pragma unroll
        for (int r = 0; r < 4; ++r) {
          int row = rl + r;
          SM[(row * 128 + cl2) ^ ((row & 7) << 3)] = f2bf(acc[m][n][r] * qscale);
        }
      }
    }
  }
  __syncthreads();

  const int swz = (lane & 7) << 3;
  bf16x8 qf[2][4];
#pragma unroll
  for (int rf = 0; rf < 2; ++rf) {
    int row = w * 32 + rf * 16 + l15;
#pragma unroll
    for (int kk = 0; kk < 4; ++kk)
      qf[rf][kk] = *(const bf16x8*)&SM[(row * 128 + kk * 32 + g * 8) ^ swz];
  }
  __syncthreads();   // all qf reads done before staging overwrites SM

  // ---------------- Phase B: R9-verbatim attn loop --------------------------
  unsigned short* PsW = SM + 32768 + w * 2048;

  const unsigned short* kSrc = Kb + ((size_t)bh * CC + (t >> 4)) * HD
                               + (((t & 15) ^ ((t >> 4) & 7)) * 8);
  const unsigned short* vSrc = Vtb + ((size_t)bh * HD + (t >> 3)) * CC
                               + (((t & 7) ^ ((t >> 3) & 7)) * 8);

  f32x4 acc_o[2][8];
#pragma unroll
  for (int rf = 0; rf < 2; ++rf)
#pragma unroll
    for (int i = 0; i < 8; ++i) acc_o[rf][i] = (f32x4){0.f, 0.f, 0.f, 0.f};
  float m_run[2][4], l_run[2][4];
#pragma unroll
  for (int rf = 0; rf < 2; ++rf)
#pragma unroll
    for (int r = 0; r < 4; ++r) { m_run[rf][r] = -1e30f; l_run[rf][r] = 0.f; }

  const float LOG2E = 1.4426950408889634f;

  int mflag = Mf[qt * 32];
  {
    char* kd = (char*)(SM)         + w * 1024;
    char* vd = (char*)(SM + 16384) + w * 1024;
#pragma unroll
    for (int i = 0; i < 4; ++i) {
      gl_lds16(kSrc + (size_t)(i * 16) * HD, kd + i * 4096);
      gl_lds16(vSrc + (size_t)i * 32 * CC,   vd + i * 4096);
    }
  }
  __syncthreads();

  int cur = 0;
  for (int c0 = 0; c0 < CC; c0 += 64) {
    const int ct = c0 >> 6;
    int nextFlag = (ct < 31) ? Mf[qt * 32 + ct + 1] : 0;
    unsigned short* KsC = SM + cur * 8192;
    unsigned short* VsC = SM + 16384 + cur * 8192;

    // 1) mask loads FIRST when this tile's mask is nonzero (oldest in FIFO)
    float mk[2][4][4];
    if (mflag) {
#pragma unroll
      for (int rf = 0; rf < 2; ++rf)
#pragma unroll
        for (int nf = 0; nf < 4; ++nf)
#pragma unroll
          for (int r = 0; r < 4; ++r)
            mk[rf][nf][r] = mask[(size_t)(q0 + w * 32 + rf * 16 + rb4 + r) * CC
                                 + c0 + nf * 16 + l15];
      __builtin_amdgcn_sched_barrier(0);
    }

    // 2) stage NEXT tile (stays in flight across the whole tile)
    if (c0 + 64 < CC) {
      char* kd = (char*)(SM + (cur ^ 1) * 8192)         + w * 1024;
      char* vd = (char*)(SM + 16384 + (cur ^ 1) * 8192) + w * 1024;
#pragma unroll
      for (int i = 0; i < 4; ++i) {
        gl_lds16(kSrc + (size_t)(c0 + 64 + i * 16) * HD, kd + i * 4096);
        gl_lds16(vSrc + (size_t)i * 32 * CC + c0 + 64,   vd + i * 4096);
      }
    }
    __builtin_amdgcn_sched_barrier(0);

    // 3) QK^T for both row-frags (K frag read once, used twice)
    f32x4 sc[2][4];
#pragma unroll
    for (int rf = 0; rf < 2; ++rf)
#pragma unroll
      for (int nf = 0; nf < 4; ++nf) sc[rf][nf] = (f32x4){0.f, 0.f, 0.f, 0.f};
    __builtin_amdgcn_s_setprio(1);
#pragma unroll
    for (int kk = 0; kk < 4; ++kk) {
#pragma unroll
      for (int nf = 0; nf < 4; ++nf) {
        bf16x8 kf = *(const bf16x8*)&KsC[((nf * 16 + l15) * 128 + kk * 32 + g * 8) ^ swz];
        sc[0][nf] = __builtin_amdgcn_mfma_f32_16x16x32_bf16(qf[0][kk], kf, sc[0][nf], 0, 0, 0);
        sc[1][nf] = __builtin_amdgcn_mfma_f32_16x16x32_bf16(qf[1][kk], kf, sc[1][nf], 0, 0, 0);
      }
    }
    __builtin_amdgcn_s_setprio(0);

    // 3b) + mask (log2 domain) — only when nonzero
    if (mflag) {
#pragma unroll
      for (int rf = 0; rf < 2; ++rf)
#pragma unroll
        for (int nf = 0; nf < 4; ++nf)
#pragma unroll
          for (int r = 0; r < 4; ++r)
            sc[rf][nf][r] = fmaf(mk[rf][nf][r], LOG2E, sc[rf][nf][r]);
    }

    // 4) softmax per row-frag (log2 domain, T13 defer-max)
#pragma unroll
    for (int rf = 0; rf < 2; ++rf) {
      int ok = 1;
      float pm[4];
#pragma unroll
      for (int r = 0; r < 4; ++r) {
        pm[r] = fmaxf(fmaxf(sc[rf][0][r], sc[rf][1][r]), fmaxf(sc[rf][2][r], sc[rf][3][r]));
        ok = ok && (pm[r] <= m_run[rf][r] + 8.0f);
      }
      if (!__all(ok)) {
#pragma unroll
        for (int r = 0; r < 4; ++r) {
          float mx = pm[r];
#pragma unroll
          for (int d = 1; d < 16; d <<= 1)
            mx = fmaxf(mx, __shfl_xor(mx, d));
          float mn = fmaxf(m_run[rf][r], mx);
          float corr = __builtin_amdgcn_exp2f(m_run[rf][r] - mn);
          m_run[rf][r] = mn;
          l_run[rf][r] *= corr;
#pragma unroll
          for (int nd = 0; nd < 8; ++nd) acc_o[rf][nd][r] *= corr;
        }
      }

#pragma unroll
      for (int r = 0; r < 4; ++r) {
        int rw = rf * 16 + rb4 + r;
        int rsw = (rw & 7) << 3;
#pragma unroll
        for (int nf = 0; nf < 4; ++nf) {
          float p = __builtin_amdgcn_exp2f(sc[rf][nf][r] - m_run[rf][r]);
          l_run[rf][r] += p;
          PsW[rw * 64 + ((nf * 16 + l15) ^ rsw)] = f2bf(p);
        }
      }
    }

    // 5) PV for both row-frags (V frag read once, used twice)
    __builtin_amdgcn_s_setprio(1);
#pragma unroll
    for (int kk = 0; kk < 2; ++kk) {
      bf16x8 pf0 = *(const bf16x8*)&PsW[((0 * 16 + l15) * 64 + kk * 32 + g * 8) ^ swz];
      bf16x8 pf1 = *(const bf16x8*)&PsW[((1 * 16 + l15) * 64 + kk * 32 + g * 8) ^ swz];
#pragma unroll
      for (int nd = 0; nd < 8; ++nd) {
        bf16x8 vf = *(const bf16x8*)&VsC[((nd * 16 + l15) * 64 + kk * 32 + g * 8) ^ swz];
        acc_o[0][nd] = __builtin_amdgcn_mfma_f32_16x16x32_bf16(pf0, vf, acc_o[0][nd], 0, 0, 0);
        acc_o[1][nd] = __builtin_amdgcn_mfma_f32_16x16x32_bf16(pf1, vf, acc_o[1][nd], 0, 0, 0);
      }
    }
    __builtin_amdgcn_s_setprio(0);
    __syncthreads();
    cur ^= 1;
    mflag = nextFlag;
  }

  // epilogue: reduce per-lane partial l across the 16-lane row group, then O/l
#pragma unroll
  for (int rf = 0; rf < 2; ++rf) {
#pragma unroll
    for (int r = 0; r < 4; ++r)
#pragma unroll
      for (int d = 1; d < 16; d <<= 1)
        l_run[rf][r] += __shfl_xor(l_run[rf][r], d);

#pragma unroll
    for (int nd = 0; nd < 8; ++nd)
#pragma unroll
      for (int r = 0; r < 4; ++r) {
        float v = acc_o[rf][nd][r] / l_run[rf][r];
        int row = q0 + w * 32 + rf * 16 + rb4 + r;
        Ob[(size_t)(bb * SS + row) * DIM + hh * HD + nd * 16 + l15] = f2bf(v);
      }
  }
}

// ---------------- launch ----------------
extern "C" void kernel_launch(void* const* d_in, const int* in_sizes, int n_in,
                              void* d_out, int out_size, void* d_ws, size_t ws_size,
                              hipStream_t stream) {
  const float* x       = (const float*)d_in[0];
  const float* mask    = (const float*)d_in[2];   // [1,1,S,C]
  const float* cache_k = (const float*)d_in[4];   // [B,C,NH,HD]
  const float* cache_v = (const float*)d_in[5];
  const float* wq      = (const float*)d_in[6];   // [DIM,DIM]
  const float* wo      = (const float*)d_in[9];
  float* out = (float*)d_out;

  // workspace layout:
  char* ws = (char*)d_ws;
  unsigned short* qbf  = (unsigned short*)(ws);                    // 16 MiB (attn out)
  unsigned short* kbf  = (unsigned short*)(ws + 16777216);         // 32 MiB
  unsigned short* vtbf = (unsigned short*)(ws + 16777216 + 33554432); // 32 MiB
  // mask flags (1 KiB) at the head of d_out — gemm_o overwrites all of
  // d_out afterwards, so no stale state leaks across replays.
  int* mflags = (int*)d_out;

  prep_b<<<6400, 256, 0, stream>>>(cache_k, kbf, cache_v, vtbf, mask, mflags);
  fused_qattn<<<BB * NH * 8, 256, 0, stream>>>(x, wq, kbf, vtbf, mask, mflags, qbf);
  gemm_o<<<dim3(DIM / 128, (BB * SS) / 128), 256, 0, stream>>>(qbf, wo, out);
}

// Round 17
// 345.381 us; speedup vs baseline: 1.3122x; 1.3122x over previous
//
#include <hip/hip_runtime.h>
#include <hip/hip_bf16.h>
#include <stdint.h>

// Attention_48241072668890: x@Wq^T -> flash-attn over fp32 KV cache -> @Wo^T
// R17 = R15 verbatim (measured 346.0us, session best). R16's f32-direct
// staging regressed (+82us): the m97 gemm phase is staging-instruction-bound,
// so f32 operands doubled the binding resource (8 gl_lds/K-step, 2x LDS,
// 2x frag-read instrs + cvt) — reverted.
// Structure: prep_b (k-conv|v^T|flags) -> prep_a (x,wq->bf16) ->
// fused_qattn (gemmQ + flash-attn, 1:1 block map, LDS handoff) ->
// conv_wo -> gemm_o.  Fusion kills the qbf round-trip; phases sequential
// per block so no vmcnt-FIFO pollution.

#define DIM   4096
#define NH    32
#define HD    128
#define BB    2
#define SS    1024
#define CC    2048

typedef __bf16 bf16x8 __attribute__((ext_vector_type(8)));
typedef float  f32x4  __attribute__((ext_vector_type(4)));

__device__ __forceinline__ unsigned short f2bf(float f) {
  union { __hip_bfloat16 h; unsigned short u; } cv;
  cv.h = __float2bfloat16(f);
  return cv.u;
}

__device__ __forceinline__ void gl_lds16(const void* g, void* l) {
  __builtin_amdgcn_global_load_lds(
      (__attribute__((address_space(1))) void*)(uintptr_t)(g),
      (__attribute__((address_space(3))) void*)(l), 16, 0, 0);
}

// ---------------- wo convert (post-fused; Wbf reused) ---------------------
__global__ void conv_f32_bf16(const float* __restrict__ in, unsigned short* __restrict__ out, int n4) {
  int i = blockIdx.x * blockDim.x + threadIdx.x;
  int stride = gridDim.x * blockDim.x;
  for (; i < n4; i += stride) {
    float4 v = reinterpret_cast<const float4*>(in)[i];
    ushort4 o;
    o.x = f2bf(v.x); o.y = f2bf(v.y); o.z = f2bf(v.z); o.w = f2bf(v.w);
    reinterpret_cast<ushort4*>(out)[i] = o;
  }
}

// ---------------- prep_a: x f32->bf16 | wq f32->bf16 (runs LAST pre-fused) -
__global__ __launch_bounds__(256) void prep_a(
    const float* __restrict__ x,  unsigned short* __restrict__ xbf,
    const float* __restrict__ wq, unsigned short* __restrict__ wbf)
{
  const int b = blockIdx.x, t = threadIdx.x;
  const float* in; unsigned short* out; int base, nthr, n4;
  if (b < 1024) { in = x;  out = xbf; base = b;        nthr = 1024 * 256; n4 = BB * SS * DIM / 4; }
  else          { in = wq; out = wbf; base = b - 1024; nthr = 2048 * 256; n4 = DIM * DIM / 4; }
  for (int i = base * 256 + t; i < n4; i += nthr) {
    float4 v = reinterpret_cast<const float4*>(in)[i];
    ushort4 o;
    o.x = f2bf(v.x); o.y = f2bf(v.y); o.z = f2bf(v.z); o.w = f2bf(v.w);
    reinterpret_cast<ushort4*>(out)[i] = o;
  }
}

// ------- prep_b: k-conv | v^T (vectorized write) | mask flags --------------
__global__ __launch_bounds__(256) void prep_b(
    const float* __restrict__ ck,  unsigned short* __restrict__ kbf,
    const float* __restrict__ cv,  unsigned short* __restrict__ vtbf,
    const float* __restrict__ mask, int* __restrict__ flags)
{
  const int b = blockIdx.x, t = threadIdx.x;

  if (b < 2048) {                 // cache_k [B,C,NH,HD] -> [B*NH,C,HD] bf16
    const int total4 = BB * NH * CC * HD / 4;
    for (int i = b * 256 + t; i < total4; i += 2048 * 256) {
      size_t o = (size_t)i * 4;
      int d  = (int)(o & (HD - 1));
      size_t r = o >> 7;
      int c  = (int)(r & (CC - 1));
      int bh = (int)(r >> 11);
      int hh = bh & (NH - 1), bb = bh >> 5;
      float4 v = *reinterpret_cast<const float4*>(ck + ((size_t)(bb * CC + c) * NH + hh) * HD + d);
      ushort4 u; u.x = f2bf(v.x); u.y = f2bf(v.y); u.z = f2bf(v.z); u.w = f2bf(v.w);
      *reinterpret_cast<ushort4*>(kbf + o) = u;
    }
  } else if (b < 6144) {          // cache_v [B,C,NH,HD] -> [B*NH,HD,C] bf16
    __shared__ float tile[64][65];
    const int e  = b - 2048;
    const int ct = e & 31, rest = e >> 5;
    const int dt = rest & 1, bh = rest >> 1;
    const int hh = bh & (NH - 1), bb = bh >> 5;
    const int c0 = ct * 64, d0 = dt * 64;
    const int tx = t & 63, ty = t >> 6;           // 64 x 4
#pragma unroll
    for (int i = 0; i < 16; ++i) {
      int cl = ty + i * 4;
      tile[cl][tx] = cv[((size_t)(bb * CC + c0 + cl) * NH + hh) * HD + d0 + tx];
    }
    __syncthreads();
    const int c4 = (t & 15) * 4, dr = t >> 4;
#pragma unroll
    for (int i = 0; i < 4; ++i) {
      int dl = dr + i * 16;
      ushort4 o;
      o.x = f2bf(tile[c4 + 0][dl]); o.y = f2bf(tile[c4 + 1][dl]);
      o.z = f2bf(tile[c4 + 2][dl]); o.w = f2bf(tile[c4 + 3][dl]);
      *reinterpret_cast<ushort4*>(&vtbf[((size_t)bh * HD + d0 + dl) * CC + c0 + c4]) = o;
    }
  } else {                        // mask flags: flag[qt*32+ct] = any != 0
    __shared__ int s[4];
    const int e  = b - 6144;
    const int qt = e >> 5, ct = e & 31;
    const int w = t >> 6;
    const float4* m4 = (const float4*)mask;
    int nz = 0;
#pragma unroll
    for (int i = 0; i < 8; ++i) {
      int idx = i * 256 + t;
      int row = idx >> 4, c4 = idx & 15;
      float4 v = m4[(size_t)(qt * 128 + row) * (CC / 4) + ct * 16 + c4];
      nz |= (v.x != 0.f) | (v.y != 0.f) | (v.z != 0.f) | (v.w != 0.f);
    }
    int wa = (int)__any(nz);
    if ((t & 63) == 0) s[w] = wa;
    __syncthreads();
    if (t == 0) flags[qt * 32 + ct] = s[0] | s[1] | s[2] | s[3];
  }
}

// ---------------- GEMM: C[M,N] = A[M,K] * B[N,K]^T  (gemmO only) ----------
template <int OUT_BF16>
__global__ __launch_bounds__(256, 2) void gemm_bt(
    const unsigned short* __restrict__ A,
    const unsigned short* __restrict__ Bw,
    void* __restrict__ Cout,
    int M, int N, int K, float scale)
{
  __shared__ __align__(16) unsigned short As[128 * 32];
  __shared__ __align__(16) unsigned short Bs[128 * 32];
  const int t = threadIdx.x;
  const int w = t >> 6, lane = t & 63;
  const int wr = w >> 1, wc = w & 1;
  const int bm0 = blockIdx.y * 128, bn0 = blockIdx.x * 128;

  const unsigned short* aSrc = A  + (size_t)(bm0 + (t >> 2)) * K + (t & 3) * 8;
  const unsigned short* bSrc = Bw + (size_t)(bn0 + (t >> 2)) * K + (t & 3) * 8;
  char* aDst = (char*)As + w * 1024;
  char* bDst = (char*)Bs + w * 1024;
  const size_t half = (size_t)64 * K;

  f32x4 acc[4][4];
#pragma unroll
  for (int m = 0; m < 4; ++m)
#pragma unroll
    for (int n = 0; n < 4; ++n) acc[m][n] = (f32x4){0.f, 0.f, 0.f, 0.f};

  for (int k0 = 0; k0 < K; k0 += 32) {
    gl_lds16(aSrc,        aDst);
    gl_lds16(aSrc + half, aDst + 4096);
    gl_lds16(bSrc,        bDst);
    gl_lds16(bSrc + half, bDst + 4096);
    aSrc += 32; bSrc += 32;
    __syncthreads();

    bf16x8 af[4], bf[4];
#pragma unroll
    for (int m = 0; m < 4; ++m)
      af[m] = *(const bf16x8*)&As[(wr * 64 + m * 16 + (lane & 15)) * 32 + (lane >> 4) * 8];
#pragma unroll
    for (int n = 0; n < 4; ++n)
      bf[n] = *(const bf16x8*)&Bs[(wc * 64 + n * 16 + (lane & 15)) * 32 + (lane >> 4) * 8];
#pragma unroll
    for (int m = 0; m < 4; ++m)
#pragma unroll
      for (int n = 0; n < 4; ++n)
        acc[m][n] = __builtin_amdgcn_mfma_f32_16x16x32_bf16(af[m], bf[n], acc[m][n], 0, 0, 0);
    __syncthreads();
  }

  const int r0 = (lane >> 4) * 4, cl = lane & 15;
#pragma unroll
  for (int m = 0; m < 4; ++m) {
#pragma unroll
    for (int n = 0; n < 4; ++n) {
      int row = bm0 + wr * 64 + m * 16 + r0;
      int col = bn0 + wc * 64 + n * 16 + cl;
#pragma unroll
      for (int r = 0; r < 4; ++r) {
        float v = acc[m][n][r] * scale;
        if (OUT_BF16) ((unsigned short*)Cout)[(size_t)(row + r) * N + col] = f2bf(v);
        else          ((float*)Cout)[(size_t)(row + r) * N + col] = v;
      }
    }
  }
}

// ------------- fused gemmQ + flash attention ------------------------------
// Phase A: m97 gemm K-loop computing this block's 128x128 Q tile (As/Bs =
//   SM[0..8192) elems). Phase H: C-frags -> Qh LDS (SM[0..16384) elems,
//   XOR-swizzled, scale*LOG2E folded) -> qf regs. Phase B: R9 attn loop.
// LDS (80KB, elem offsets): Ks[b]=SM+b*8192 per-cur; Vs[b]=SM+16384+b*8192;
//   Ps wave-private = SM+32768+w*2048.
__global__ __launch_bounds__(256, 2) void fused_qattn(
    const unsigned short* __restrict__ Ax,     // xbf [B*S, DIM]
    const unsigned short* __restrict__ Wq,     // wq bf16 [DIM, DIM]
    const unsigned short* __restrict__ Kb,
    const unsigned short* __restrict__ Vtb,
    const float* __restrict__ mask,
    const int* __restrict__ Mf,
    unsigned short* __restrict__ Ob)           // qbf (attn out)
{
  __shared__ __align__(16) unsigned short SM[40960];   // 80 KB

  const int t = threadIdx.x, w = t >> 6, lane = t & 63;
  const int lg = (blockIdx.x & 7) * 64 + (blockIdx.x >> 3);  // XCD-chunked remap
  const int qt = lg & 7, bh = lg >> 3;
  const int hh = bh & (NH - 1), bb = bh >> 5;
  const int q0 = qt * 128;
  const int l15 = lane & 15, g = lane >> 4;
  const int rb4 = g * 4;
  const int wr = w >> 1, wc = w & 1;

  // ---------------- Phase A: gemm — Q tile = xbf[bm0..+128,:] @ Wq[bn0..+128,:]^T
  const int bm0 = bb * SS + q0;       // global A row
  const int bn0 = hh * HD;            // global B row (= Q column block)
  {
    unsigned short* As = SM;                 // [128*32]
    unsigned short* Bs = SM + 4096;          // [128*32]
    const unsigned short* aSrc = Ax + (size_t)(bm0 + (t >> 2)) * DIM + (t & 3) * 8;
    const unsigned short* bSrc = Wq + (size_t)(bn0 + (t >> 2)) * DIM + (t & 3) * 8;
    char* aDst = (char*)As + w * 1024;
    char* bDst = (char*)Bs + w * 1024;
    const size_t half = (size_t)64 * DIM;

    f32x4 acc[4][4];
#pragma unroll
    for (int m = 0; m < 4; ++m)
#pragma unroll
      for (int n = 0; n < 4; ++n) acc[m][n] = (f32x4){0.f, 0.f, 0.f, 0.f};

    for (int k0 = 0; k0 < DIM; k0 += 32) {
      gl_lds16(aSrc,        aDst);
      gl_lds16(aSrc + half, aDst + 4096);
      gl_lds16(bSrc,        bDst);
      gl_lds16(bSrc + half, bDst + 4096);
      aSrc += 32; bSrc += 32;
      __syncthreads();

      bf16x8 af[4], bf[4];
#pragma unroll
      for (int m = 0; m < 4; ++m)
        af[m] = *(const bf16x8*)&As[(wr * 64 + m * 16 + l15) * 32 + g * 8];
#pragma unroll
      for (int n = 0; n < 4; ++n)
        bf[n] = *(const bf16x8*)&Bs[(wc * 64 + n * 16 + l15) * 32 + g * 8];
#pragma unroll
      for (int m = 0; m < 4; ++m)
#pragma unroll
        for (int n = 0; n < 4; ++n)
          acc[m][n] = __builtin_amdgcn_mfma_f32_16x16x32_bf16(af[m], bf[n], acc[m][n], 0, 0, 0);
      __syncthreads();
    }

    // ---------------- Phase H: C-frags -> Qh (swizzled) -> qf registers
    // write: elem idx = (row*128 + col) ^ ((row&7)<<3), scale*LOG2E folded
    const float qscale = 0.12751744682f;     // (1/sqrt(128)) * log2(e)
    const int r0 = g * 4;
#pragma unroll
    for (int m = 0; m < 4; ++m) {
#pragma unroll
      for (int n = 0; n < 4; ++n) {
        int rl = wr * 64 + m * 16 + r0;
        int cl2 = wc * 64 + n * 16 + l15;
#pragma unroll
        for (int r = 0; r < 4; ++r) {
          int row = rl + r;
          SM[(row * 128 + cl2) ^ ((row & 7) << 3)] = f2bf(acc[m][n][r] * qscale);
        }
      }
    }
  }
  __syncthreads();

  // qf read in A-frag layout: row = w*32+rf*16+l15, k-chunk kk*32+g*8;
  // (row&7)==(lane&7) so the XOR is the same swz as the write.
  const int swz = (lane & 7) << 3;
  bf16x8 qf[2][4];
#pragma unroll
  for (int rf = 0; rf < 2; ++rf) {
    int row = w * 32 + rf * 16 + l15;
#pragma unroll
    for (int kk = 0; kk < 4; ++kk)
      qf[rf][kk] = *(const bf16x8*)&SM[(row * 128 + kk * 32 + g * 8) ^ swz];
  }
  __syncthreads();   // all qf reads done before staging overwrites SM

  // ---------------- Phase B: R9-verbatim attn loop --------------------------
  // LDS offsets (elems): Ks[b] = SM + b*8192; Vs[b] = SM + 16384 + b*8192;
  // Ps(wave) = SM + 32768 + w*2048.  (No pointer arrays: hipcc rejects
  // brace-init of generic pointers from an LDS symbol.)
  unsigned short* PsW = SM + 32768 + w * 2048;

  const unsigned short* kSrc = Kb + ((size_t)bh * CC + (t >> 4)) * HD
                               + (((t & 15) ^ ((t >> 4) & 7)) * 8);
  const unsigned short* vSrc = Vtb + ((size_t)bh * HD + (t >> 3)) * CC
                               + (((t & 7) ^ ((t >> 3) & 7)) * 8);

  f32x4 acc_o[2][8];
#pragma unroll
  for (int rf = 0; rf < 2; ++rf)
#pragma unroll
    for (int i = 0; i < 8; ++i) acc_o[rf][i] = (f32x4){0.f, 0.f, 0.f, 0.f};
  float m_run[2][4], l_run[2][4];
#pragma unroll
  for (int rf = 0; rf < 2; ++rf)
#pragma unroll
    for (int r = 0; r < 4; ++r) { m_run[rf][r] = -1e30f; l_run[rf][r] = 0.f; }

  const float LOG2E = 1.4426950408889634f;

  int mflag = Mf[qt * 32];
  {
    char* kd = (char*)(SM)         + w * 1024;
    char* vd = (char*)(SM + 16384) + w * 1024;
#pragma unroll
    for (int i = 0; i < 4; ++i) {
      gl_lds16(kSrc + (size_t)(i * 16) * HD, kd + i * 4096);
      gl_lds16(vSrc + (size_t)i * 32 * CC,   vd + i * 4096);
    }
  }
  __syncthreads();

  int cur = 0;
  for (int c0 = 0; c0 < CC; c0 += 64) {
    const int ct = c0 >> 6;
    int nextFlag = (ct < 31) ? Mf[qt * 32 + ct + 1] : 0;
    unsigned short* KsC = SM + cur * 8192;
    unsigned short* VsC = SM + 16384 + cur * 8192;

    // 1) mask loads FIRST when this tile's mask is nonzero (oldest in FIFO)
    float mk[2][4][4];
    if (mflag) {
#pragma unroll
      for (int rf = 0; rf < 2; ++rf)
#pragma unroll
        for (int nf = 0; nf < 4; ++nf)
#pragma unroll
          for (int r = 0; r < 4; ++r)
            mk[rf][nf][r] = mask[(size_t)(q0 + w * 32 + rf * 16 + rb4 + r) * CC
                                 + c0 + nf * 16 + l15];
      __builtin_amdgcn_sched_barrier(0);
    }

    // 2) stage NEXT tile (stays in flight across the whole tile)
    if (c0 + 64 < CC) {
      char* kd = (char*)(SM + (cur ^ 1) * 8192)         + w * 1024;
      char* vd = (char*)(SM + 16384 + (cur ^ 1) * 8192) + w * 1024;
#pragma unroll
      for (int i = 0; i < 4; ++i) {
        gl_lds16(kSrc + (size_t)(c0 + 64 + i * 16) * HD, kd + i * 4096);
        gl_lds16(vSrc + (size_t)i * 32 * CC + c0 + 64,   vd + i * 4096);
      }
    }
    __builtin_amdgcn_sched_barrier(0);

    // 3) QK^T for both row-frags (K frag read once, used twice)
    f32x4 sc[2][4];
#pragma unroll
    for (int rf = 0; rf < 2; ++rf)
#pragma unroll
      for (int nf = 0; nf < 4; ++nf) sc[rf][nf] = (f32x4){0.f, 0.f, 0.f, 0.f};
    __builtin_amdgcn_s_setprio(1);
#pragma unroll
    for (int kk = 0; kk < 4; ++kk) {
#pragma unroll
      for (int nf = 0; nf < 4; ++nf) {
        bf16x8 kf = *(const bf16x8*)&KsC[((nf * 16 + l15) * 128 + kk * 32 + g * 8) ^ swz];
        sc[0][nf] = __builtin_amdgcn_mfma_f32_16x16x32_bf16(qf[0][kk], kf, sc[0][nf], 0, 0, 0);
        sc[1][nf] = __builtin_amdgcn_mfma_f32_16x16x32_bf16(qf[1][kk], kf, sc[1][nf], 0, 0, 0);
      }
    }
    __builtin_amdgcn_s_setprio(0);

    // 3b) + mask (log2 domain) — only when nonzero
    if (mflag) {
#pragma unroll
      for (int rf = 0; rf < 2; ++rf)
#pragma unroll
        for (int nf = 0; nf < 4; ++nf)
#pragma unroll
          for (int r = 0; r < 4; ++r)
            sc[rf][nf][r] = fmaf(mk[rf][nf][r], LOG2E, sc[rf][nf][r]);
    }

    // 4) softmax per row-frag (log2 domain, T13 defer-max)
#pragma unroll
    for (int rf = 0; rf < 2; ++rf) {
      int ok = 1;
      float pm[4];
#pragma unroll
      for (int r = 0; r < 4; ++r) {
        pm[r] = fmaxf(fmaxf(sc[rf][0][r], sc[rf][1][r]), fmaxf(sc[rf][2][r], sc[rf][3][r]));
        ok = ok && (pm[r] <= m_run[rf][r] + 8.0f);
      }
      if (!__all(ok)) {
#pragma unroll
        for (int r = 0; r < 4; ++r) {
          float mx = pm[r];
#pragma unroll
          for (int d = 1; d < 16; d <<= 1)
            mx = fmaxf(mx, __shfl_xor(mx, d));
          float mn = fmaxf(m_run[rf][r], mx);
          float corr = __builtin_amdgcn_exp2f(m_run[rf][r] - mn);
          m_run[rf][r] = mn;
          l_run[rf][r] *= corr;
#pragma unroll
          for (int nd = 0; nd < 8; ++nd) acc_o[rf][nd][r] *= corr;
        }
      }

#pragma unroll
      for (int r = 0; r < 4; ++r) {
        int rw = rf * 16 + rb4 + r;
        int rsw = (rw & 7) << 3;
#pragma unroll
        for (int nf = 0; nf < 4; ++nf) {
          float p = __builtin_amdgcn_exp2f(sc[rf][nf][r] - m_run[rf][r]);
          l_run[rf][r] += p;
          PsW[rw * 64 + ((nf * 16 + l15) ^ rsw)] = f2bf(p);
        }
      }
    }

    // 5) PV for both row-frags (V frag read once, used twice)
    __builtin_amdgcn_s_setprio(1);
#pragma unroll
    for (int kk = 0; kk < 2; ++kk) {
      bf16x8 pf0 = *(const bf16x8*)&PsW[((0 * 16 + l15) * 64 + kk * 32 + g * 8) ^ swz];
      bf16x8 pf1 = *(const bf16x8*)&PsW[((1 * 16 + l15) * 64 + kk * 32 + g * 8) ^ swz];
#pragma unroll
      for (int nd = 0; nd < 8; ++nd) {
        bf16x8 vf = *(const bf16x8*)&VsC[((nd * 16 + l15) * 64 + kk * 32 + g * 8) ^ swz];
        acc_o[0][nd] = __builtin_amdgcn_mfma_f32_16x16x32_bf16(pf0, vf, acc_o[0][nd], 0, 0, 0);
        acc_o[1][nd] = __builtin_amdgcn_mfma_f32_16x16x32_bf16(pf1, vf, acc_o[1][nd], 0, 0, 0);
      }
    }
    __builtin_amdgcn_s_setprio(0);
    __syncthreads();
    cur ^= 1;
    mflag = nextFlag;
  }

  // epilogue: reduce per-lane partial l across the 16-lane row group, then O/l
#pragma unroll
  for (int rf = 0; rf < 2; ++rf) {
#pragma unroll
    for (int r = 0; r < 4; ++r)
#pragma unroll
      for (int d = 1; d < 16; d <<= 1)
        l_run[rf][r] += __shfl_xor(l_run[rf][r], d);

#pragma unroll
    for (int nd = 0; nd < 8; ++nd)
#pragma unroll
      for (int r = 0; r < 4; ++r) {
        float v = acc_o[rf][nd][r] / l_run[rf][r];
        int row = q0 + w * 32 + rf * 16 + rb4 + r;
        Ob[(size_t)(bb * SS + row) * DIM + hh * HD + nd * 16 + l15] = f2bf(v);
      }
  }
}

// ---------------- launch ----------------
extern "C" void kernel_launch(void* const* d_in, const int* in_sizes, int n_in,
                              void* d_out, int out_size, void* d_ws, size_t ws_size,
                              hipStream_t stream) {
  const float* x       = (const float*)d_in[0];
  const float* mask    = (const float*)d_in[2];   // [1,1,S,C]
  const float* cache_k = (const float*)d_in[4];   // [B,C,NH,HD]
  const float* cache_v = (const float*)d_in[5];
  const float* wq      = (const float*)d_in[6];   // [DIM,DIM]
  const float* wo      = (const float*)d_in[9];
  float* out = (float*)d_out;

  // workspace layout (128 MiB):
  char* ws = (char*)d_ws;
  unsigned short* Wbf  = (unsigned short*)(ws);                                  // 32 MiB (wq, later wo)
  unsigned short* xbf  = (unsigned short*)(ws + 33554432);                       // 16 MiB (x bf16, read-only in fused)
  unsigned short* qbf  = (unsigned short*)(ws + 33554432 + 16777216);            // 16 MiB (attn out)
  unsigned short* kbf  = (unsigned short*)(ws + 33554432 + 2 * 16777216);        // 32 MiB
  unsigned short* vtbf = (unsigned short*)(ws + 2 * 33554432 + 2 * 16777216);    // 32 MiB
  // mask flags (1 KiB) at the head of d_out — final gemm overwrites all of
  // d_out afterwards, so no stale state leaks across replays.
  int* mflags = (int*)d_out;

  // prep_b first; prep_a last so xbf/Wbf are L3-hot for the fused gemm phase
  prep_b<<<6400, 256, 0, stream>>>(cache_k, kbf, cache_v, vtbf, mask, mflags);
  prep_a<<<3072, 256, 0, stream>>>(x, xbf, wq, Wbf);
  fused_qattn<<<BB * NH * 8, 256, 0, stream>>>(xbf, Wbf, kbf, vtbf, mask, mflags, qbf);
  conv_f32_bf16<<<2048, 256, 0, stream>>>(wo, Wbf, DIM * DIM / 4);
  dim3 gg(DIM / 128, (BB * SS) / 128);
  gemm_bt<0><<<gg, 256, 0, stream>>>(qbf, Wbf, out, BB * SS, DIM, DIM, 1.0f);
}